// Round 1
// baseline (5871.910 us; speedup 1.0000x reference)
//
#include <hip/hip_runtime.h>
#include <hip/hip_bf16.h>

// ---------------------------------------------------------------------------
// NonLocalBlock1D: fp32 correctness-first baseline.
// Pipeline:
//   pe table -> x+pe -> relu(Wtr@x) -> 2 dilated tconvs (shifted GEMMs)
//   -> per branch: g/th/ph proj, S=th^T ph, softmax rows, Y=gx@S^T
//   -> wy = W_W @ Y -> per-channel mean/var norm -> +x residual
// One tiled fp32 GEMM template (64x64 tile, BK=16, 256 thr, 4x4 microtile)
// with A-transpose / B-transpose / column-shift / accumulate / relu variants.
// ---------------------------------------------------------------------------

#define B_ 8
#define C_ 512
#define T_ 2048
#define I_ 256

// ---------------------------------------------------------------------------
// GEMM: C[z][m][n] (+)= sum_k Aval(m,k)*Bval(k,n) + bias[m]
//  TA=0: Aval = A[z][m*lda + k]      (row-major M x K)
//  TA=1: Aval = A[z][k*lda + m]      (row-major K x M)
//  TB=0: Bval = B[z][k*ldb + n+shift] (zero outside [0,bLimit))
//  TB=1: Bval = B[z][n*ldb + k]      (row-major N x K)
// Grid: (N/64, M/64, batch)
// ---------------------------------------------------------------------------
template <bool TA, bool TB, bool RELU, bool ACC>
__global__ __launch_bounds__(256) void gemm_f32(
    const float* __restrict__ A, long aB, int lda,
    const float* __restrict__ Bm, long bB, int ldb,
    const float* __restrict__ bias,
    float* __restrict__ Cm, long cB, int ldc,
    int K, int bShift, int bLimit)
{
    __shared__ float As[16][64];
    __shared__ float Bs[16][64];
    const int z = blockIdx.z;
    const float* Ab = A + (long)z * aB;
    const float* Bb = Bm + (long)z * bB;
    float* Cb = Cm + (long)z * cB;
    const int m0 = blockIdx.y * 64;
    const int n0 = blockIdx.x * 64;
    const int tid = threadIdx.x;
    const int tx = tid & 15, ty = tid >> 4;

    float acc[4][4] = {};

    for (int k0 = 0; k0 < K; k0 += 16) {
        // ---- stage A tile: As[k][m]
        if (!TA) {
            const int m = tid >> 2, k4 = (tid & 3) << 2;
            const float4 v = *(const float4*)(Ab + (long)(m0 + m) * lda + (k0 + k4));
            As[k4 + 0][m] = v.x; As[k4 + 1][m] = v.y;
            As[k4 + 2][m] = v.z; As[k4 + 3][m] = v.w;
        } else {
            const int k = tid >> 4, m4 = (tid & 15) << 2;
            *(float4*)&As[k][m4] =
                *(const float4*)(Ab + (long)(k0 + k) * lda + (m0 + m4));
        }
        // ---- stage B tile: Bs[k][n]
        if (!TB) {
            const int k = tid >> 4, n4 = (tid & 15) << 2;
            const int col = n0 + n4 + bShift;
            const float* src = Bb + (long)(k0 + k) * ldb + col;
            float4 v;
            if (bShift == 0) {
                v = *(const float4*)src;
            } else {
                v.x = ((unsigned)(col + 0) < (unsigned)bLimit) ? src[0] : 0.f;
                v.y = ((unsigned)(col + 1) < (unsigned)bLimit) ? src[1] : 0.f;
                v.z = ((unsigned)(col + 2) < (unsigned)bLimit) ? src[2] : 0.f;
                v.w = ((unsigned)(col + 3) < (unsigned)bLimit) ? src[3] : 0.f;
            }
            *(float4*)&Bs[k][n4] = v;
        } else {
            const int n = tid >> 2, k4 = (tid & 3) << 2;
            const float4 v = *(const float4*)(Bb + (long)(n0 + n) * ldb + (k0 + k4));
            Bs[k4 + 0][n] = v.x; Bs[k4 + 1][n] = v.y;
            Bs[k4 + 2][n] = v.z; Bs[k4 + 3][n] = v.w;
        }
        __syncthreads();

        #pragma unroll
        for (int k = 0; k < 16; ++k) {
            const float4 a = *(const float4*)&As[k][ty << 2];
            const float4 b = *(const float4*)&Bs[k][tx << 2];
            acc[0][0] += a.x * b.x; acc[0][1] += a.x * b.y;
            acc[0][2] += a.x * b.z; acc[0][3] += a.x * b.w;
            acc[1][0] += a.y * b.x; acc[1][1] += a.y * b.y;
            acc[1][2] += a.y * b.z; acc[1][3] += a.y * b.w;
            acc[2][0] += a.z * b.x; acc[2][1] += a.z * b.y;
            acc[2][2] += a.z * b.z; acc[2][3] += a.z * b.w;
            acc[3][0] += a.w * b.x; acc[3][1] += a.w * b.y;
            acc[3][2] += a.w * b.z; acc[3][3] += a.w * b.w;
        }
        __syncthreads();
    }

    #pragma unroll
    for (int i = 0; i < 4; ++i) {
        const int m = m0 + (ty << 2) + i;
        const float bv = bias ? bias[m] : 0.f;
        float4 r;
        r.x = acc[i][0] + bv; r.y = acc[i][1] + bv;
        r.z = acc[i][2] + bv; r.w = acc[i][3] + bv;
        if (RELU) {
            r.x = fmaxf(r.x, 0.f); r.y = fmaxf(r.y, 0.f);
            r.z = fmaxf(r.z, 0.f); r.w = fmaxf(r.w, 0.f);
        }
        float* dst = Cb + (long)m * ldc + n0 + (tx << 2);
        if (ACC) {
            const float4 o = *(const float4*)dst;
            r.x += o.x; r.y += o.y; r.z += o.z; r.w += o.w;
        }
        *(float4*)dst = r;
    }
}

// ---------------------------------------------------------------------------
__global__ __launch_bounds__(256) void pe_kernel(float* __restrict__ pe)
{
    const int idx = blockIdx.x * 256 + threadIdx.x;  // C_*T_ = 1,048,576
    if (idx >= C_ * T_) return;
    const int c = idx / T_, t = idx % T_;
    const float i2 = (float)(c & ~1);
    const float freq = expf(-(9.210340371976184f / (float)C_) * i2);
    const float ang = (float)t * freq;
    pe[idx] = (c & 1) ? cosf(ang) : sinf(ang);
}

__global__ __launch_bounds__(256) void add_pos(
    const float* __restrict__ x, const float* __restrict__ pe,
    float* __restrict__ xpe)
{
    const long i4 = (long)blockIdx.x * 256 + threadIdx.x;  // BCT/4
    if (i4 >= (long)B_ * C_ * T_ / 4) return;
    const long i = i4 * 4;
    const int c = (int)((i / T_) & (C_ - 1));
    const int t = (int)(i % T_);
    const float4 xv = ((const float4*)x)[i4];
    const float4 pv = *(const float4*)(pe + (long)c * T_ + t);
    float4 r;
    r.x = xv.x + pv.x; r.y = xv.y + pv.y;
    r.z = xv.z + pv.z; r.w = xv.w + pv.w;
    ((float4*)xpe)[i4] = r;
}

__global__ __launch_bounds__(256) void softmax_rows(float* __restrict__ S)
{
    __shared__ float sm[4];
    float* row = S + (long)blockIdx.x * T_;
    const int tid = threadIdx.x;
    float v[8];
    float mx = -1e30f;
    #pragma unroll
    for (int j = 0; j < 8; ++j) {
        v[j] = row[tid + j * 256];
        mx = fmaxf(mx, v[j]);
    }
    #pragma unroll
    for (int o = 32; o; o >>= 1) mx = fmaxf(mx, __shfl_xor(mx, o, 64));
    if ((tid & 63) == 0) sm[tid >> 6] = mx;
    __syncthreads();
    mx = fmaxf(fmaxf(sm[0], sm[1]), fmaxf(sm[2], sm[3]));
    __syncthreads();
    float s = 0.f;
    #pragma unroll
    for (int j = 0; j < 8; ++j) {
        v[j] = __expf(v[j] - mx);
        s += v[j];
    }
    #pragma unroll
    for (int o = 32; o; o >>= 1) s += __shfl_xor(s, o, 64);
    if ((tid & 63) == 0) sm[tid >> 6] = s;
    __syncthreads();
    s = sm[0] + sm[1] + sm[2] + sm[3];
    const float inv = 1.f / s;
    #pragma unroll
    for (int j = 0; j < 8; ++j) row[tid + j * 256] = v[j] * inv;
}

__global__ __launch_bounds__(256) void stats_kernel(
    const float* __restrict__ wy, float* __restrict__ mean,
    float* __restrict__ rstd)
{
    __shared__ float sm[8];
    const int o = blockIdx.x, tid = threadIdx.x;
    float s = 0.f, ss = 0.f;
    for (int idx = tid; idx < B_ * T_; idx += 256) {
        const int b = idx >> 11, t = idx & (T_ - 1);
        const float vv = wy[((long)b * C_ + o) * T_ + t];
        s += vv; ss += vv * vv;
    }
    #pragma unroll
    for (int off = 32; off; off >>= 1) {
        s += __shfl_xor(s, off, 64);
        ss += __shfl_xor(ss, off, 64);
    }
    if ((tid & 63) == 0) { sm[tid >> 6] = s; sm[4 + (tid >> 6)] = ss; }
    __syncthreads();
    if (tid == 0) {
        s = sm[0] + sm[1] + sm[2] + sm[3];
        ss = sm[4] + sm[5] + sm[6] + sm[7];
        const float mu = s / (float)(B_ * T_);
        const float var = ss / (float)(B_ * T_) - mu * mu;
        mean[o] = mu;
        rstd[o] = rsqrtf(var + 1e-5f);
    }
}

__global__ __launch_bounds__(256) void final_kernel(
    float* __restrict__ out, const float* __restrict__ x1,
    const float* __restrict__ mean, const float* __restrict__ rstd,
    const float* __restrict__ gamma, const float* __restrict__ beta)
{
    const long i4 = (long)blockIdx.x * 256 + threadIdx.x;
    if (i4 >= (long)B_ * C_ * T_ / 4) return;
    const long i = i4 * 4;
    const int c = (int)((i / T_) & (C_ - 1));
    const float4 w = ((const float4*)out)[i4];
    const float4 xv = ((const float4*)x1)[i4];
    const float mu = mean[c];
    const float a = rstd[c] * gamma[c];
    const float bb = beta[c];
    float4 r;
    r.x = (w.x - mu) * a + bb + xv.x;
    r.y = (w.y - mu) * a + bb + xv.y;
    r.z = (w.z - mu) * a + bb + xv.z;
    r.w = (w.w - mu) * a + bb + xv.w;
    ((float4*)out)[i4] = r;
}

// ---------------------------------------------------------------------------
extern "C" void kernel_launch(void* const* d_in, const int* in_sizes, int n_in,
                              void* d_out, int out_size, void* d_ws, size_t ws_size,
                              hipStream_t stream)
{
    const float* x    = (const float*)d_in[0];
    const float* w_tr = (const float*)d_in[1];
    const float* b_tr = (const float*)d_in[2];
    const float* w_tc = (const float*)d_in[3];   // (2, C, 3, C)
    const float* w_g  = (const float*)d_in[4];   // (3, I, C)
    const float* b_g  = (const float*)d_in[5];
    const float* w_th = (const float*)d_in[6];
    const float* b_th = (const float*)d_in[7];
    const float* w_ph = (const float*)d_in[8];
    const float* b_ph = (const float*)d_in[9];
    const float* w_W  = (const float*)d_in[10];  // (C, 3I)
    const float* b_W  = (const float*)d_in[11];
    const float* gamma = (const float*)d_in[12];
    const float* beta  = (const float*)d_in[13];
    float* out = (float*)d_out;
    float* ws  = (float*)d_ws;

    const long CT  = (long)C_ * T_;        // 1,048,576
    const long BCT = (long)B_ * CT;        // 8,388,608
    const long IT  = (long)I_ * T_;        // 524,288
    const long TT  = (long)T_ * T_;        // 4,194,304

    // workspace layout (floats)
    float* pe   = ws;
    float* xpe  = pe  + CT;
    float* x1   = xpe + BCT;
    float* tx0  = x1  + BCT;
    float* tx1  = tx0 + BCT;
    float* gx   = tx1 + BCT;
    float* th   = gx  + (long)B_ * IT;
    float* ph   = th  + (long)B_ * IT;
    float* Y    = ph  + (long)B_ * IT;     // 3*B*IT
    float* meanb = Y  + 3 * (long)B_ * IT;
    float* rstdb = meanb + C_;
    float* S    = rstdb + C_;

    const long needFull = (S - ws) + (long)B_ * TT;   // batched scores
    const bool batched = ws_size >= (size_t)needFull * sizeof(float);

    // 1. positional encoding table + add
    pe_kernel<<<(C_ * T_ + 255) / 256, 256, 0, stream>>>(pe);
    add_pos<<<(int)(BCT / 4 / 256), 256, 0, stream>>>(x, pe, xpe);

    // 2. x1 = relu(w_tr @ xpe + b_tr)
    gemm_f32<false, false, true, false><<<dim3(T_ / 64, C_ / 64, B_), 256, 0, stream>>>(
        w_tr, 0, C_, xpe, CT, T_, b_tr, x1, CT, T_, C_, 0, T_);

    // 3. temporal convs (dilation 1 and 2): 3 shifted GEMMs each, accumulated
    for (int i = 0; i < 2; ++i) {
        float* dst = (i == 0) ? tx0 : tx1;
        const int d = i + 1;
        for (int kh = 0; kh < 3; ++kh) {
            const float* A = w_tc + (long)i * C_ * 3 * C_ + (long)kh * C_;
            const int shift = (kh - 1) * d;
            if (kh == 0)
                gemm_f32<false, false, false, false><<<dim3(T_ / 64, C_ / 64, B_), 256, 0, stream>>>(
                    A, 0, 3 * C_, x1, CT, T_, nullptr, dst, CT, T_, C_, shift, T_);
            else
                gemm_f32<false, false, false, true><<<dim3(T_ / 64, C_ / 64, B_), 256, 0, stream>>>(
                    A, 0, 3 * C_, x1, CT, T_, nullptr, dst, CT, T_, C_, shift, T_);
        }
    }

    // 4. branches
    for (int br = 0; br < 3; ++br) {
        const float* tx = (br == 0) ? tx0 : (br == 1) ? tx1 : x1;
        gemm_f32<false, false, false, false><<<dim3(T_ / 64, I_ / 64, B_), 256, 0, stream>>>(
            w_g + (long)br * I_ * C_, 0, C_, tx, CT, T_, b_g + br * I_, gx, IT, T_, C_, 0, T_);
        gemm_f32<false, false, false, false><<<dim3(T_ / 64, I_ / 64, B_), 256, 0, stream>>>(
            w_th + (long)br * I_ * C_, 0, C_, tx, CT, T_, b_th + br * I_, th, IT, T_, C_, 0, T_);
        gemm_f32<false, false, false, false><<<dim3(T_ / 64, I_ / 64, B_), 256, 0, stream>>>(
            w_ph + (long)br * I_ * C_, 0, C_, tx, CT, T_, b_ph + br * I_, ph, IT, T_, C_, 0, T_);

        if (batched) {
            // S[b][t][s] = sum_i th[b][i][t] * ph[b][i][s]
            gemm_f32<true, false, false, false><<<dim3(T_ / 64, T_ / 64, B_), 256, 0, stream>>>(
                th, IT, T_, ph, IT, T_, nullptr, S, TT, T_, I_, 0, T_);
            softmax_rows<<<B_ * T_, 256, 0, stream>>>(S);
            // Y[b][br*I+i][t] = sum_s gx[b][i][s] * S[b][t][s]
            gemm_f32<false, true, false, false><<<dim3(T_ / 64, I_ / 64, B_), 256, 0, stream>>>(
                gx, IT, T_, S, TT, T_, nullptr, Y + (long)br * IT, 3 * IT, T_, T_, 0, T_);
        } else {
            for (int b = 0; b < B_; ++b) {
                gemm_f32<true, false, false, false><<<dim3(T_ / 64, T_ / 64, 1), 256, 0, stream>>>(
                    th + (long)b * IT, 0, T_, ph + (long)b * IT, 0, T_, nullptr, S, 0, T_, I_, 0, T_);
                softmax_rows<<<T_, 256, 0, stream>>>(S);
                gemm_f32<false, true, false, false><<<dim3(T_ / 64, I_ / 64, 1), 256, 0, stream>>>(
                    gx + (long)b * IT, 0, T_, S, 0, T_, nullptr,
                    Y + (long)b * 3 * IT + (long)br * IT, 0, T_, T_, 0, T_);
            }
        }
    }

    // 5. wy = w_W @ Y + b_W   (into d_out)
    gemm_f32<false, false, false, false><<<dim3(T_ / 64, C_ / 64, B_), 256, 0, stream>>>(
        w_W, 0, 3 * I_, Y, 3 * IT, T_, b_W, out, CT, T_, 3 * I_, 0, T_);

    // 6. per-channel mean/var over (b, t)
    stats_kernel<<<C_, 256, 0, stream>>>(out, meanb, rstdb);

    // 7. normalize + affine + residual (in place on d_out)
    final_kernel<<<(int)(BCT / 4 / 256), 256, 0, stream>>>(out, x1, meanb, rstdb, gamma, beta);
}

// Round 6
// 665.599 us; speedup vs baseline: 8.8220x; 8.8220x over previous
//
#include <hip/hip_runtime.h>

#define B_ 8
#define C_ 512
#define T_ 2048
#define I_ 256

typedef _Float16 f16x8 __attribute__((ext_vector_type(8)));
typedef float f32x4 __attribute__((ext_vector_type(4)));
typedef unsigned short u16;
typedef unsigned short u16x4 __attribute__((ext_vector_type(4)));

__device__ __forceinline__ u16 f2h(float f) {           // RNE f32->f16
    _Float16 h = (_Float16)f;
    return *(u16*)&h;
}
__device__ __forceinline__ float h2f(u16 u) {
    _Float16 h = *(_Float16*)&u;
    return (float)h;
}

#define AS1 __attribute__((address_space(1)))
#define AS3 __attribute__((address_space(3)))
__device__ __forceinline__ void gload16(const u16* g, u16* l) {
    __builtin_amdgcn_global_load_lds((const AS1 void*)(const void*)g,
                                     (AS3 void*)(void*)l, 16, 0, 0);
}

// ---------------------------------------------------------------------------
// fp16 MFMA GEMM: out[z][m][n] = sum_k A[z][m][k] * B[z][n][k] (+ bias[m])
//   A: (M,K) row-major f16, batch stride aB (0 = shared weights)
//   B: (N,K) row-major f16 ("B^T input" form), batch stride bB
// Tile 128x128, BK=64, 256 thr = 4 waves (2x2), wave = 64x64 = 4x4 frags.
// LDS [row][k] linear rows of 128B, XOR swizzle: 16B-slot s holds k16 = s^(row&7).
// global_load_lds: linear LDS dest + inverse-swizzled per-lane global source.
// WMODE bits: 1 = f32 normal (Cf), 2 = f16 normal (Cn), 4 = f16 transposed (Ct).
// ---------------------------------------------------------------------------
template <int WMODE, bool BIAS, bool RELU>
__global__ __launch_bounds__(256) void mfma_gemm(
    const u16* __restrict__ A, long aB, int lda,
    const u16* __restrict__ Bm, long bB, int ldb,
    const float* __restrict__ bias,
    float* __restrict__ Cf, u16* __restrict__ Cn, long cB, int ldc,
    u16* __restrict__ Ct, long ctB, int ldct, int ctOff,
    int K)
{
    __shared__ u16 sA[128 * 64];
    __shared__ u16 sB[128 * 64];
    const int z = blockIdx.z;
    const int m0 = blockIdx.y * 128, n0 = blockIdx.x * 128;
    const int tid = threadIdx.x;
    const int lane = tid & 63, wv = tid >> 6;
    const int wm = wv >> 1, wn = wv & 1;
    const int l15 = lane & 15, l4 = lane >> 4;

    const u16* Ab = A + (long)z * aB + (long)m0 * lda;
    const u16* Bb = Bm + (long)z * bB + (long)n0 * ldb;

    // staging geometry: linear LDS byte L = wv*4096 + ch*1024 + lane*16
    //   row = L>>7, slot = (L>>4)&7 = lane&7 ; row&7 = lane>>3
    const int srow = wv * 32 + (lane >> 3);          // + ch*8
    const int sk16 = (lane & 7) ^ (lane >> 3);       // inverse swizzle on source

    f32x4 acc[4][4];
    #pragma unroll
    for (int i = 0; i < 4; ++i)
        #pragma unroll
        for (int j = 0; j < 4; ++j) acc[i][j] = (f32x4){0.f, 0.f, 0.f, 0.f};

    for (int k0 = 0; k0 < K; k0 += 64) {
        #pragma unroll
        for (int ch = 0; ch < 4; ++ch) {
            gload16(Ab + (long)(srow + ch * 8) * lda + k0 + sk16 * 8,
                    &sA[wv * 2048 + ch * 512]);
            gload16(Bb + (long)(srow + ch * 8) * ldb + k0 + sk16 * 8,
                    &sB[wv * 2048 + ch * 512]);
        }
        __syncthreads();   // compiler drains vmcnt(0) before barrier
        #pragma unroll
        for (int kk = 0; kk < 2; ++kk) {
            f16x8 af[4], bfr[4];
            #pragma unroll
            for (int f = 0; f < 4; ++f) {
                const int ra = wm * 64 + f * 16 + l15;
                af[f] = *(const f16x8*)&sA[ra * 64 + ((((kk << 2) | l4) ^ (ra & 7)) << 3)];
                const int rb = wn * 64 + f * 16 + l15;
                bfr[f] = *(const f16x8*)&sB[rb * 64 + ((((kk << 2) | l4) ^ (rb & 7)) << 3)];
            }
            #pragma unroll
            for (int mi = 0; mi < 4; ++mi)
                #pragma unroll
                for (int ni = 0; ni < 4; ++ni)
                    acc[mi][ni] = __builtin_amdgcn_mfma_f32_16x16x32_f16(
                        af[mi], bfr[ni], acc[mi][ni], 0, 0, 0);
        }
        __syncthreads();
    }

    // epilogue: D element (m = m0+wm*64+mi*16+l4*4+r, n = n0+wn*64+ni*16+l15)
    #pragma unroll
    for (int mi = 0; mi < 4; ++mi) {
        const int mb = m0 + wm * 64 + mi * 16 + l4 * 4;
        float bv[4] = {0.f, 0.f, 0.f, 0.f};
        if (BIAS) {
            #pragma unroll
            for (int r = 0; r < 4; ++r) bv[r] = bias[mb + r];
        }
        #pragma unroll
        for (int ni = 0; ni < 4; ++ni) {
            const int nb = n0 + wn * 64 + ni * 16 + l15;
            float v[4];
            #pragma unroll
            for (int r = 0; r < 4; ++r) {
                v[r] = acc[mi][ni][r] + bv[r];
                if (RELU) v[r] = fmaxf(v[r], 0.f);
            }
            if (WMODE & 1) {
                #pragma unroll
                for (int r = 0; r < 4; ++r)
                    Cf[(long)z * cB + (long)(mb + r) * ldc + nb] = v[r];
            }
            if (WMODE & 2) {
                #pragma unroll
                for (int r = 0; r < 4; ++r)
                    Cn[(long)z * cB + (long)(mb + r) * ldc + nb] = f2h(v[r]);
            }
            if (WMODE & 4) {
                u16x4 pk;
                #pragma unroll
                for (int r = 0; r < 4; ++r) pk[r] = f2h(v[r]);
                *(u16x4*)&Ct[(long)z * ctB + (long)nb * ldct + ctOff + mb] = pk;
            }
        }
    }
}

// ---------------------------------------------------------------------------
__global__ __launch_bounds__(256) void to_f16(
    const float* __restrict__ s, u16* __restrict__ d, long n4)
{
    const long i = (long)blockIdx.x * 256 + threadIdx.x;
    if (i >= n4) return;
    const float4 v = ((const float4*)s)[i];
    u16x4 pk = {f2h(v.x), f2h(v.y), f2h(v.z), f2h(v.w)};
    ((u16x4*)d)[i] = pk;
}

__global__ __launch_bounds__(256) void peT_kernel(float* __restrict__ peT)
{
    const int idx = blockIdx.x * 256 + threadIdx.x;  // T_*C_
    const int c = idx & (C_ - 1), t = idx >> 9;
    const float i2 = (float)(c & ~1);
    const float freq = expf(-(9.210340371976184f / (float)C_) * i2);
    const float ang = (float)t * freq;
    peT[idx] = (c & 1) ? cosf(ang) : sinf(ang);
}

// xpeT[b][t][c] = x[b][c][t] + peT[t][c], f16 out. 64x64 LDS-tiled transpose.
__global__ __launch_bounds__(256) void xpose_add(
    const float* __restrict__ x, const float* __restrict__ peT,
    u16* __restrict__ xpeT)
{
    __shared__ float tile[64][65];
    const int b = blockIdx.z;
    const int t0 = blockIdx.x * 64, c0 = blockIdx.y * 64;
    const int rr = threadIdx.x >> 4, cc4 = (threadIdx.x & 15) << 2;
    #pragma unroll
    for (int p = 0; p < 4; ++p) {
        const int row = rr + p * 16;   // c-local
        const float4 v = *(const float4*)&x[((long)b * C_ + c0 + row) * T_ + t0 + cc4];
        tile[row][cc4 + 0] = v.x; tile[row][cc4 + 1] = v.y;
        tile[row][cc4 + 2] = v.z; tile[row][cc4 + 3] = v.w;
    }
    __syncthreads();
    #pragma unroll
    for (int p = 0; p < 4; ++p) {
        const int tt = rr + p * 16;    // t-local
        const int gt = t0 + tt;
        const float4 pv = *(const float4*)&peT[(long)gt * C_ + c0 + cc4];
        u16x4 pk = {f2h(tile[cc4 + 0][tt] + pv.x),
                    f2h(tile[cc4 + 1][tt] + pv.y),
                    f2h(tile[cc4 + 2][tt] + pv.z),
                    f2h(tile[cc4 + 3][tt] + pv.w)};
        *(u16x4*)&xpeT[((long)b * T_ + gt) * C_ + c0 + cc4] = pk;
    }
}

// BpT[b][t][kh*C+c] = x1T[b][t+(kh-1)d][c] (0 outside), 8 f16 per thread
__global__ __launch_bounds__(256) void build_bpt(
    const u16* __restrict__ x1T, u16* __restrict__ BpT, int d)
{
    const long i8 = (long)blockIdx.x * 256 + threadIdx.x;  // B*T*3C/8
    const long flat = i8 << 3;
    const int col = (int)(flat % (3 * C_));
    const long rest = flat / (3 * C_);
    const int t = (int)(rest & (T_ - 1));
    const int b = (int)(rest >> 11);
    const int kh = col >> 9;
    const int c = col & (C_ - 1);
    const int ts = t + (kh - 1) * d;
    uint4 v = make_uint4(0u, 0u, 0u, 0u);
    if ((unsigned)ts < (unsigned)T_)
        v = *(const uint4*)&x1T[((long)b * T_ + ts) * C_ + c];
    *(uint4*)&BpT[flat] = v;
}

// in-place row softmax on f16 (B*T rows of length T)
__global__ __launch_bounds__(256) void softmax_f16(u16* __restrict__ S)
{
    __shared__ float sm[4];
    u16* row = S + (long)blockIdx.x * T_;
    const int tid = threadIdx.x, lane = tid & 63, wv = tid >> 6;
    uint4 pv = ((uint4*)row)[tid];
    const u16* pb = (const u16*)&pv;
    float v[8], mx = -1e30f;
    #pragma unroll
    for (int j = 0; j < 8; ++j) { v[j] = h2f(pb[j]); mx = fmaxf(mx, v[j]); }
    #pragma unroll
    for (int o = 32; o; o >>= 1) mx = fmaxf(mx, __shfl_xor(mx, o, 64));
    if (lane == 0) sm[wv] = mx;
    __syncthreads();
    mx = fmaxf(fmaxf(sm[0], sm[1]), fmaxf(sm[2], sm[3]));
    __syncthreads();
    float s = 0.f;
    #pragma unroll
    for (int j = 0; j < 8; ++j) { v[j] = __expf(v[j] - mx); s += v[j]; }
    #pragma unroll
    for (int o = 32; o; o >>= 1) s += __shfl_xor(s, o, 64);
    if (lane == 0) sm[wv] = s;
    __syncthreads();
    s = sm[0] + sm[1] + sm[2] + sm[3];
    const float inv = 1.f / s;
    u16x4 o0, o1;
    #pragma unroll
    for (int j = 0; j < 4; ++j) o0[j] = f2h(v[j] * inv);
    #pragma unroll
    for (int j = 0; j < 4; ++j) o1[j] = f2h(v[4 + j] * inv);
    uint4 ov;
    ((u16x4*)&ov)[0] = o0; ((u16x4*)&ov)[1] = o1;
    ((uint4*)row)[tid] = ov;
}

__global__ __launch_bounds__(256) void stats_kernel(
    const float* __restrict__ wy, float* __restrict__ mean,
    float* __restrict__ rstd)
{
    __shared__ float sm[8];
    const int o = blockIdx.x, tid = threadIdx.x;
    float s = 0.f, ss = 0.f;
    for (int idx = tid; idx < B_ * T_; idx += 256) {
        const int b = idx >> 11, t = idx & (T_ - 1);
        const float vv = wy[((long)b * C_ + o) * T_ + t];
        s += vv; ss += vv * vv;
    }
    #pragma unroll
    for (int off = 32; off; off >>= 1) {
        s += __shfl_xor(s, off, 64);
        ss += __shfl_xor(ss, off, 64);
    }
    if ((tid & 63) == 0) { sm[tid >> 6] = s; sm[4 + (tid >> 6)] = ss; }
    __syncthreads();
    if (tid == 0) {
        s = sm[0] + sm[1] + sm[2] + sm[3];
        ss = sm[4] + sm[5] + sm[6] + sm[7];
        const float mu = s / (float)(B_ * T_);
        const float var = ss / (float)(B_ * T_) - mu * mu;
        mean[o] = mu;
        rstd[o] = rsqrtf(var + 1e-5f);
    }
}

__global__ __launch_bounds__(256) void final_kernel(
    float* __restrict__ out, const u16* __restrict__ x1n,
    const float* __restrict__ mean, const float* __restrict__ rstd,
    const float* __restrict__ gamma, const float* __restrict__ beta)
{
    const long i4 = (long)blockIdx.x * 256 + threadIdx.x;  // BCT/4
    const long i = i4 * 4;
    const int c = (int)((i / T_) & (C_ - 1));
    const float4 w = ((const float4*)out)[i4];
    const uint2 xv = ((const uint2*)x1n)[i4];
    const u16* xb = (const u16*)&xv;
    const float mu = mean[c];
    const float a = rstd[c] * gamma[c];
    const float bb = beta[c];
    float4 r;
    r.x = (w.x - mu) * a + bb + h2f(xb[0]);
    r.y = (w.y - mu) * a + bb + h2f(xb[1]);
    r.z = (w.z - mu) * a + bb + h2f(xb[2]);
    r.w = (w.w - mu) * a + bb + h2f(xb[3]);
    ((float4*)out)[i4] = r;
}

// ---------------------------------------------------------------------------
extern "C" void kernel_launch(void* const* d_in, const int* in_sizes, int n_in,
                              void* d_out, int out_size, void* d_ws, size_t ws_size,
                              hipStream_t stream)
{
    const float* x    = (const float*)d_in[0];
    const float* w_tr = (const float*)d_in[1];
    const float* b_tr = (const float*)d_in[2];
    const float* w_tc = (const float*)d_in[3];
    const float* w_g  = (const float*)d_in[4];
    const float* b_g  = (const float*)d_in[5];
    const float* w_th = (const float*)d_in[6];
    const float* b_th = (const float*)d_in[7];
    const float* w_ph = (const float*)d_in[8];
    const float* b_ph = (const float*)d_in[9];
    const float* w_W  = (const float*)d_in[10];
    const float* b_W  = (const float*)d_in[11];
    const float* gamma = (const float*)d_in[12];
    const float* beta  = (const float*)d_in[13];
    float* out = (float*)d_out;

    char* pp = (char*)d_ws;
    auto nextp = [&](long bytes) { char* r = pp; pp += (bytes + 255) & ~255L; return r; };
    float* peT = (float*)nextp(4L * T_ * C_);
    u16* xpeT  = (u16*)nextp(2L * B_ * T_ * C_);
    u16* x1n   = (u16*)nextp(2L * B_ * C_ * T_);
    u16* x1T   = (u16*)nextp(2L * B_ * T_ * C_);
    u16* tx0T  = (u16*)nextp(2L * B_ * T_ * C_);
    u16* tx1T  = (u16*)nextp(2L * B_ * T_ * C_);
    u16* BpT   = (u16*)nextp(2L * B_ * T_ * 3 * C_);
    u16* gxb   = (u16*)nextp(2L * B_ * I_ * T_);
    u16* thT   = (u16*)nextp(2L * B_ * T_ * I_);
    u16* phT   = (u16*)nextp(2L * B_ * T_ * I_);
    u16* SF    = (u16*)nextp(2L * B_ * T_ * T_);
    u16* YT    = (u16*)nextp(2L * B_ * T_ * 3 * I_);
    u16* w_trb = (u16*)nextp(2L * C_ * C_);
    u16* w_tcb = (u16*)nextp(2L * 2 * C_ * 3 * C_);
    u16* w_gb  = (u16*)nextp(2L * 3 * I_ * C_);
    u16* w_thb = (u16*)nextp(2L * 3 * I_ * C_);
    u16* w_phb = (u16*)nextp(2L * 3 * I_ * C_);
    u16* w_Wb  = (u16*)nextp(2L * C_ * 3 * I_);
    float* meanb = (float*)nextp(4L * C_);
    float* rstdb = (float*)nextp(4L * C_);

    const long TC = (long)T_ * C_;
    const long CT = (long)C_ * T_;
    const long TI = (long)T_ * I_;
    const long IT = (long)I_ * T_;
    const long TT = (long)T_ * T_;

    auto cvt = [&](const float* s, u16* d, long n) {
        to_f16<<<(int)((n / 4 + 255) / 256), 256, 0, stream>>>(s, d, n / 4);
    };
    cvt(w_tr, w_trb, (long)C_ * C_);
    cvt(w_tc, w_tcb, 2L * C_ * 3 * C_);
    cvt(w_g,  w_gb,  3L * I_ * C_);
    cvt(w_th, w_thb, 3L * I_ * C_);
    cvt(w_ph, w_phb, 3L * I_ * C_);
    cvt(w_W,  w_Wb,  (long)C_ * 3 * I_);

    peT_kernel<<<(T_ * C_) / 256, 256, 0, stream>>>(peT);
    xpose_add<<<dim3(T_ / 64, C_ / 64, B_), 256, 0, stream>>>(x, peT, xpeT);

    // x1 = relu(w_tr @ xpe + b_tr): writes x1n (C,T) + x1T (T,C)
    mfma_gemm<6, true, true><<<dim3(16, 4, 8), 256, 0, stream>>>(
        w_trb, 0, C_, xpeT, TC, C_, b_tr,
        nullptr, x1n, CT, T_, x1T, TC, C_, 0, C_);

    // temporal convs as single K=1536 GEMMs vs shifted-stacked x1T
    build_bpt<<<(int)(B_ * T_ * 3 * C_ / 8 / 256), 256, 0, stream>>>(x1T, BpT, 1);
    mfma_gemm<4, false, false><<<dim3(16, 4, 8), 256, 0, stream>>>(
        w_tcb, 0, 3 * C_, BpT, 3 * TC, 3 * C_, nullptr,
        nullptr, nullptr, 0, 0, tx0T, TC, C_, 0, 3 * C_);
    build_bpt<<<(int)(B_ * T_ * 3 * C_ / 8 / 256), 256, 0, stream>>>(x1T, BpT, 2);
    mfma_gemm<4, false, false><<<dim3(16, 4, 8), 256, 0, stream>>>(
        w_tcb + (long)C_ * 3 * C_, 0, 3 * C_, BpT, 3 * TC, 3 * C_, nullptr,
        nullptr, nullptr, 0, 0, tx1T, TC, C_, 0, 3 * C_);

    const u16* txTs[3] = {tx0T, tx1T, x1T};
    for (int br = 0; br < 3; ++br) {
        const u16* tb = txTs[br];
        mfma_gemm<2, true, false><<<dim3(16, 2, 8), 256, 0, stream>>>(
            w_gb + (long)br * I_ * C_, 0, C_, tb, TC, C_, b_g + br * I_,
            nullptr, gxb, IT, T_, nullptr, 0, 0, 0, C_);
        mfma_gemm<4, true, false><<<dim3(16, 2, 8), 256, 0, stream>>>(
            w_thb + (long)br * I_ * C_, 0, C_, tb, TC, C_, b_th + br * I_,
            nullptr, nullptr, 0, 0, thT, TI, I_, 0, C_);
        mfma_gemm<4, true, false><<<dim3(16, 2, 8), 256, 0, stream>>>(
            w_phb + (long)br * I_ * C_, 0, C_, tb, TC, C_, b_ph + br * I_,
            nullptr, nullptr, 0, 0, phT, TI, I_, 0, C_);
        // S[t][s] = sum_i thT[t][i] * phT[s][i]  -> f16, then row softmax
        mfma_gemm<2, false, false><<<dim3(16, 16, 8), 256, 0, stream>>>(
            thT, TI, I_, phT, TI, I_, nullptr,
            nullptr, SF, TT, T_, nullptr, 0, 0, 0, I_);
        softmax_f16<<<B_ * T_, 256, 0, stream>>>(SF);
        // Y[i][t] = sum_s gx[i][s] * F[t][s] -> YT[t][br*I+i]
        mfma_gemm<4, false, false><<<dim3(16, 2, 8), 256, 0, stream>>>(
            gxb, IT, T_, SF, TT, T_, nullptr,
            nullptr, nullptr, 0, 0, YT, 3 * TI, 3 * I_, br * I_, T_);
    }

    // wy = w_W @ Y + b_W -> d_out (f32)
    mfma_gemm<1, true, false><<<dim3(16, 4, 8), 256, 0, stream>>>(
        w_Wb, 0, 3 * I_, YT, 3 * TI, 3 * I_, b_W,
        out, nullptr, CT, T_, nullptr, 0, 0, 0, 3 * I_);

    stats_kernel<<<C_, 256, 0, stream>>>(out, meanb, rstdb);
    final_kernel<<<(int)(B_ * C_ * T_ / 4 / 256), 256, 0, stream>>>(
        out, x1n, meanb, rstdb, gamma, beta);
}

// Round 8
// 539.908 us; speedup vs baseline: 10.8758x; 1.2328x over previous
//
#include <hip/hip_runtime.h>

#define B_ 8
#define C_ 512
#define T_ 2048
#define I_ 256

typedef _Float16 f16x8 __attribute__((ext_vector_type(8)));
typedef float f32x4 __attribute__((ext_vector_type(4)));
typedef unsigned short u16;
typedef unsigned short u16x4 __attribute__((ext_vector_type(4)));

__device__ __forceinline__ u16 f2h(float f) {
    _Float16 h = (_Float16)f;
    return *(u16*)&h;
}
__device__ __forceinline__ float h2f(u16 u) {
    _Float16 h = *(_Float16*)&u;
    return (float)h;
}

#define AS1 __attribute__((address_space(1)))
#define AS3 __attribute__((address_space(3)))
__device__ __forceinline__ void gload16(const u16* g, u16* l) {
    __builtin_amdgcn_global_load_lds((const AS1 void*)(const void*)g,
                                     (AS3 void*)(void*)l, 16, 0, 0);
}

// ---------------------------------------------------------------------------
// fp16 MFMA GEMM: out[z][m][n] = sum_k A[zw][m][k] * B[z][n][k] (+ bias[zw][m])
//   zw = z / aZdiv (weight batching over leading grid.z groups)
// Tile 128x128, BK=64, 256 thr = 4 waves. LDS slot^(row&7) swizzle.
// WMODE bits: 1 = f32 normal (Cf), 2 = f16 normal (Cn), 4 = f16 transposed (Ct).
// ---------------------------------------------------------------------------
template <int WMODE, bool BIAS, bool RELU>
__global__ __launch_bounds__(256) void mfma_gemm(
    const u16* __restrict__ A, long aB, int aZdiv, int lda,
    const u16* __restrict__ Bm, long bB, int ldb,
    const float* __restrict__ bias, int biasStride,
    float* __restrict__ Cf, u16* __restrict__ Cn, long cB, int ldc,
    u16* __restrict__ Ct, long ctB, int ldct, int ctOff,
    int K)
{
    __shared__ u16 sA[128 * 64];
    __shared__ u16 sB[128 * 64];
    const int z = blockIdx.z;
    const int zw = z / aZdiv;
    const int m0 = blockIdx.y * 128, n0 = blockIdx.x * 128;
    const int tid = threadIdx.x;
    const int lane = tid & 63, wv = tid >> 6;
    const int wm = wv >> 1, wn = wv & 1;
    const int l15 = lane & 15, l4 = lane >> 4;

    const u16* Ab = A + (long)zw * aB + (long)m0 * lda;
    const u16* Bb = Bm + (long)z * bB + (long)n0 * ldb;

    const int srow = wv * 32 + (lane >> 3);
    const int sk16 = (lane & 7) ^ (lane >> 3);

    f32x4 acc[4][4];
    #pragma unroll
    for (int i = 0; i < 4; ++i)
        #pragma unroll
        for (int j = 0; j < 4; ++j) acc[i][j] = (f32x4){0.f, 0.f, 0.f, 0.f};

    for (int k0 = 0; k0 < K; k0 += 64) {
        #pragma unroll
        for (int ch = 0; ch < 4; ++ch) {
            gload16(Ab + (long)(srow + ch * 8) * lda + k0 + sk16 * 8,
                    &sA[wv * 2048 + ch * 512]);
            gload16(Bb + (long)(srow + ch * 8) * ldb + k0 + sk16 * 8,
                    &sB[wv * 2048 + ch * 512]);
        }
        __syncthreads();
        #pragma unroll
        for (int kk = 0; kk < 2; ++kk) {
            f16x8 af[4], bfr[4];
            #pragma unroll
            for (int f = 0; f < 4; ++f) {
                const int ra = wm * 64 + f * 16 + l15;
                af[f] = *(const f16x8*)&sA[ra * 64 + ((((kk << 2) | l4) ^ (ra & 7)) << 3)];
                const int rb = wn * 64 + f * 16 + l15;
                bfr[f] = *(const f16x8*)&sB[rb * 64 + ((((kk << 2) | l4) ^ (rb & 7)) << 3)];
            }
            #pragma unroll
            for (int mi = 0; mi < 4; ++mi)
                #pragma unroll
                for (int ni = 0; ni < 4; ++ni)
                    acc[mi][ni] = __builtin_amdgcn_mfma_f32_16x16x32_f16(
                        af[mi], bfr[ni], acc[mi][ni], 0, 0, 0);
        }
        __syncthreads();
    }

    #pragma unroll
    for (int mi = 0; mi < 4; ++mi) {
        const int mb = m0 + wm * 64 + mi * 16 + l4 * 4;
        float bv[4] = {0.f, 0.f, 0.f, 0.f};
        if (BIAS) {
            const float* bp = bias + (long)zw * biasStride;
            #pragma unroll
            for (int r = 0; r < 4; ++r) bv[r] = bp[mb + r];
        }
        #pragma unroll
        for (int ni = 0; ni < 4; ++ni) {
            const int nb = n0 + wn * 64 + ni * 16 + l15;
            float v[4];
            #pragma unroll
            for (int r = 0; r < 4; ++r) {
                v[r] = acc[mi][ni][r] + bv[r];
                if (RELU) v[r] = fmaxf(v[r], 0.f);
            }
            if (WMODE & 1) {
                #pragma unroll
                for (int r = 0; r < 4; ++r)
                    Cf[(long)z * cB + (long)(mb + r) * ldc + nb] = v[r];
            }
            if (WMODE & 2) {
                #pragma unroll
                for (int r = 0; r < 4; ++r)
                    Cn[(long)z * cB + (long)(mb + r) * ldc + nb] = f2h(v[r]);
            }
            if (WMODE & 4) {
                u16x4 pk;
                #pragma unroll
                for (int r = 0; r < 4; ++r) pk[r] = f2h(v[r]);
                *(u16x4*)&Ct[(long)z * ctB + (long)nb * ldct + ctOff + mb] = pk;
            }
        }
    }
}

// ---------------------------------------------------------------------------
// Flash attention: per (q-tile, z=br*8+b) block, 512 thr = 8 waves.
// Q = thA[z] (T,I), K = phA[z] (T,I), V^T = gxA[z] (I,T) (B-operand ready).
// Out YT[b][t][br*I + dv], online softmax over s, KVB=64.
// ---------------------------------------------------------------------------
__global__ __launch_bounds__(512) void flash_attn(
    const u16* __restrict__ thA, const u16* __restrict__ phA,
    const u16* __restrict__ gxA, u16* __restrict__ YT)
{
    __shared__ u16 sK[64 * 256];     // [s][k]  32 KB, slot^(s&7) swizzle
    __shared__ u16 sV[256 * 64];     // [dv][s] 32 KB, slot^(dv&7) swizzle
    __shared__ u16 sP[8 * 16 * 64];  // per-wave [t][s] 16 KB, slot^(t&7)

    // XCD-bijective swizzle: 384 blocks, 48 per XCD -> all 16 q-tiles of a z
    // land on one XCD (K/V re-reads become L2 hits).
    const int flat = blockIdx.y * 16 + blockIdx.x;
    const int swz = (flat & 7) * 48 + (flat >> 3);
    const int qb = swz & 15, z = swz >> 4;
    const int br = z >> 3, b = z & 7;
    const int t0 = qb * 128;
    const int tid = threadIdx.x;
    const int lane = tid & 63, wv = tid >> 6;
    const int l15 = lane & 15, l4 = lane >> 4;

    const u16* Qz = thA + (long)z * (T_ * I_);
    const u16* Kz = phA + (long)z * (T_ * I_);
    const u16* Vz = gxA + (long)z * ((long)I_ * T_);

    // Q fragments in regs: rows t0 + wv*16 + l15, k = ks*32 + l4*8
    f16x8 qf[8];
    {
        const u16* qrow = Qz + (long)(t0 + wv * 16 + l15) * I_ + l4 * 8;
        #pragma unroll
        for (int ks = 0; ks < 8; ++ks) qf[ks] = *(const f16x8*)(qrow + ks * 32);
    }

    f32x4 oacc[16];
    #pragma unroll
    for (int i = 0; i < 16; ++i) oacc[i] = (f32x4){0.f, 0.f, 0.f, 0.f};
    float mrun[4] = {-1e30f, -1e30f, -1e30f, -1e30f};
    float lrun[4] = {0.f, 0.f, 0.f, 0.f};

    const int krow = tid >> 5;                    // + is*16
    const int kk16 = (tid & 31) ^ (krow & 7);
    const int vrow = tid >> 3;                    // + is*64
    const int vk16 = (tid & 7) ^ (vrow & 7);

    for (int s0 = 0; s0 < T_; s0 += 64) {
        #pragma unroll
        for (int is = 0; is < 4; ++is) {
            gload16(Kz + (long)(s0 + is * 16 + krow) * I_ + kk16 * 8,
                    &sK[is * 4096 + tid * 8]);
            gload16(Vz + (long)(is * 64 + vrow) * T_ + s0 + vk16 * 8,
                    &sV[is * 4096 + tid * 8]);
        }
        __syncthreads();

        // S = Q K^T: rows t (wave's 16), cols s (64) = 4 n-frags
        f32x4 sacc[4];
        #pragma unroll
        for (int nf = 0; nf < 4; ++nf) sacc[nf] = (f32x4){0.f, 0.f, 0.f, 0.f};
        #pragma unroll
        for (int nf = 0; nf < 4; ++nf) {
            const int srow = nf * 16 + l15;
            #pragma unroll
            for (int ks = 0; ks < 8; ++ks) {
                f16x8 kf = *(const f16x8*)&sK[srow * 256 + ((((ks << 2) | l4) ^ (srow & 7)) << 3)];
                sacc[nf] = __builtin_amdgcn_mfma_f32_16x16x32_f16(qf[ks], kf, sacc[nf], 0, 0, 0);
            }
        }

        // online softmax; C/D row = l4*4+r, col = l15 + nf*16
        float scale[4];
        #pragma unroll
        for (int r = 0; r < 4; ++r) {
            float v0 = fmaxf(fmaxf(sacc[0][r], sacc[1][r]),
                             fmaxf(sacc[2][r], sacc[3][r]));
            #pragma unroll
            for (int o = 8; o; o >>= 1) v0 = fmaxf(v0, __shfl_xor(v0, o, 64));
            const float mnew = fmaxf(mrun[r], v0);
            scale[r] = __expf(mrun[r] - mnew);
            mrun[r] = mnew;
        }
        float rsum[4] = {0.f, 0.f, 0.f, 0.f};
        #pragma unroll
        for (int nf = 0; nf < 4; ++nf) {
            #pragma unroll
            for (int r = 0; r < 4; ++r) {
                const float p = __expf(sacc[nf][r] - mrun[r]);
                rsum[r] += p;
                const int tl = l4 * 4 + r;
                const int sl = l15 + nf * 16;
                sP[wv * 1024 + tl * 64 + ((((sl >> 3) ^ (tl & 7)) << 3) | (sl & 7))] = f2h(p);
            }
        }
        #pragma unroll
        for (int r = 0; r < 4; ++r) {
            #pragma unroll
            for (int o = 8; o; o >>= 1) rsum[r] += __shfl_xor(rsum[r], o, 64);
            lrun[r] = lrun[r] * scale[r] + rsum[r];
        }
        #pragma unroll
        for (int nf = 0; nf < 16; ++nf)
            #pragma unroll
            for (int r = 0; r < 4; ++r) oacc[nf][r] *= scale[r];

        // PV: A = P (row t = l15, k = s), B = V (row dv, k = s)
        f16x8 pa[2];
        #pragma unroll
        for (int kk = 0; kk < 2; ++kk)
            pa[kk] = *(const f16x8*)&sP[wv * 1024 + l15 * 64 + ((((kk << 2) | l4) ^ (l15 & 7)) << 3)];
        #pragma unroll
        for (int nf = 0; nf < 16; ++nf) {
            const int dvr = nf * 16 + l15;
            #pragma unroll
            for (int kk = 0; kk < 2; ++kk) {
                f16x8 vf = *(const f16x8*)&sV[dvr * 64 + ((((kk << 2) | l4) ^ (dvr & 7)) << 3)];
                oacc[nf] = __builtin_amdgcn_mfma_f32_16x16x32_f16(pa[kk], vf, oacc[nf], 0, 0, 0);
            }
        }
        __syncthreads();
    }

    // normalize + store YT[b][t][br*I + dv]
    #pragma unroll
    for (int r = 0; r < 4; ++r) {
        const float inv = 1.f / lrun[r];
        const int t = t0 + wv * 16 + l4 * 4 + r;
        u16* dst = YT + ((long)b * T_ + t) * (3 * I_) + br * I_ + l15;
        #pragma unroll
        for (int nf = 0; nf < 16; ++nf)
            dst[nf * 16] = f2h(oacc[nf][r] * inv);
    }
}

// ---------------------------------------------------------------------------
__global__ __launch_bounds__(256) void to_f16(
    const float* __restrict__ s, u16* __restrict__ d, long n4)
{
    const long i = (long)blockIdx.x * 256 + threadIdx.x;
    if (i >= n4) return;
    const float4 v = ((const float4*)s)[i];
    u16x4 pk = {f2h(v.x), f2h(v.y), f2h(v.z), f2h(v.w)};
    ((u16x4*)d)[i] = pk;
}

__global__ __launch_bounds__(256) void peT_kernel(float* __restrict__ peT)
{
    const int idx = blockIdx.x * 256 + threadIdx.x;
    const int c = idx & (C_ - 1), t = idx >> 9;
    const float i2 = (float)(c & ~1);
    const float freq = expf(-(9.210340371976184f / (float)C_) * i2);
    const float ang = (float)t * freq;
    peT[idx] = (c & 1) ? cosf(ang) : sinf(ang);
}

__global__ __launch_bounds__(256) void xpose_add(
    const float* __restrict__ x, const float* __restrict__ peT,
    u16* __restrict__ xpeT)
{
    __shared__ float tile[64][65];
    const int b = blockIdx.z;
    const int t0 = blockIdx.x * 64, c0 = blockIdx.y * 64;
    const int rr = threadIdx.x >> 4, cc4 = (threadIdx.x & 15) << 2;
    #pragma unroll
    for (int p = 0; p < 4; ++p) {
        const int row = rr + p * 16;
        const float4 v = *(const float4*)&x[((long)b * C_ + c0 + row) * T_ + t0 + cc4];
        tile[row][cc4 + 0] = v.x; tile[row][cc4 + 1] = v.y;
        tile[row][cc4 + 2] = v.z; tile[row][cc4 + 3] = v.w;
    }
    __syncthreads();
    #pragma unroll
    for (int p = 0; p < 4; ++p) {
        const int tt = rr + p * 16;
        const int gt = t0 + tt;
        const float4 pv = *(const float4*)&peT[(long)gt * C_ + c0 + cc4];
        u16x4 pk = {f2h(tile[cc4 + 0][tt] + pv.x),
                    f2h(tile[cc4 + 1][tt] + pv.y),
                    f2h(tile[cc4 + 2][tt] + pv.z),
                    f2h(tile[cc4 + 3][tt] + pv.w)};
        *(u16x4*)&xpeT[((long)b * T_ + gt) * C_ + c0 + cc4] = pk;
    }
}

__global__ __launch_bounds__(256) void build_bpt(
    const u16* __restrict__ x1T, u16* __restrict__ BpT, int d)
{
    const long i8 = (long)blockIdx.x * 256 + threadIdx.x;
    const long flat = i8 << 3;
    const int col = (int)(flat % (3 * C_));
    const long rest = flat / (3 * C_);
    const int t = (int)(rest & (T_ - 1));
    const int b = (int)(rest >> 11);
    const int kh = col >> 9;
    const int c = col & (C_ - 1);
    const int ts = t + (kh - 1) * d;
    uint4 v = make_uint4(0u, 0u, 0u, 0u);
    if ((unsigned)ts < (unsigned)T_)
        v = *(const uint4*)&x1T[((long)b * T_ + ts) * C_ + c];
    *(uint4*)&BpT[flat] = v;
}

__global__ __launch_bounds__(256) void stats_kernel(
    const float* __restrict__ wy, float* __restrict__ mean,
    float* __restrict__ rstd)
{
    __shared__ float sm[8];
    const int o = blockIdx.x, tid = threadIdx.x;
    float s = 0.f, ss = 0.f;
    for (int idx = tid; idx < B_ * T_; idx += 256) {
        const int b = idx >> 11, t = idx & (T_ - 1);
        const float vv = wy[((long)b * C_ + o) * T_ + t];
        s += vv; ss += vv * vv;
    }
    #pragma unroll
    for (int off = 32; off; off >>= 1) {
        s += __shfl_xor(s, off, 64);
        ss += __shfl_xor(ss, off, 64);
    }
    if ((tid & 63) == 0) { sm[tid >> 6] = s; sm[4 + (tid >> 6)] = ss; }
    __syncthreads();
    if (tid == 0) {
        s = sm[0] + sm[1] + sm[2] + sm[3];
        ss = sm[4] + sm[5] + sm[6] + sm[7];
        const float mu = s / (float)(B_ * T_);
        const float var = ss / (float)(B_ * T_) - mu * mu;
        mean[o] = mu;
        rstd[o] = rsqrtf(var + 1e-5f);
    }
}

__global__ __launch_bounds__(256) void final_kernel(
    float* __restrict__ out, const u16* __restrict__ x1n,
    const float* __restrict__ mean, const float* __restrict__ rstd,
    const float* __restrict__ gamma, const float* __restrict__ beta)
{
    const long i4 = (long)blockIdx.x * 256 + threadIdx.x;
    const long i = i4 * 4;
    const int c = (int)((i / T_) & (C_ - 1));
    const float4 w = ((const float4*)out)[i4];
    const uint2 xv = ((const uint2*)x1n)[i4];
    const u16* xb = (const u16*)&xv;
    const float mu = mean[c];
    const float a = rstd[c] * gamma[c];
    const float bb = beta[c];
    float4 r;
    r.x = (w.x - mu) * a + bb + h2f(xb[0]);
    r.y = (w.y - mu) * a + bb + h2f(xb[1]);
    r.z = (w.z - mu) * a + bb + h2f(xb[2]);
    r.w = (w.w - mu) * a + bb + h2f(xb[3]);
    ((float4*)out)[i4] = r;
}

// ---------------------------------------------------------------------------
extern "C" void kernel_launch(void* const* d_in, const int* in_sizes, int n_in,
                              void* d_out, int out_size, void* d_ws, size_t ws_size,
                              hipStream_t stream)
{
    const float* x    = (const float*)d_in[0];
    const float* w_tr = (const float*)d_in[1];
    const float* b_tr = (const float*)d_in[2];
    const float* w_tc = (const float*)d_in[3];
    const float* w_g  = (const float*)d_in[4];
    const float* b_g  = (const float*)d_in[5];
    const float* w_th = (const float*)d_in[6];
    const float* b_th = (const float*)d_in[7];
    const float* w_ph = (const float*)d_in[8];
    const float* b_ph = (const float*)d_in[9];
    const float* w_W  = (const float*)d_in[10];
    const float* b_W  = (const float*)d_in[11];
    const float* gamma = (const float*)d_in[12];
    const float* beta  = (const float*)d_in[13];
    float* out = (float*)d_out;

    char* pp = (char*)d_ws;
    auto nextp = [&](long bytes) { char* r = pp; pp += (bytes + 255) & ~255L; return r; };
    const long TC = (long)T_ * C_;
    const long CT = (long)C_ * T_;
    const long TI = (long)T_ * I_;
    const long IT = (long)I_ * T_;

    float* peT  = (float*)nextp(4L * T_ * C_);
    u16* xpeT   = (u16*)nextp(2L * B_ * TC);
    u16* x1n    = (u16*)nextp(2L * B_ * CT);
    u16* txAll  = (u16*)nextp(2L * 3 * B_ * TC);   // (br, b, T, C); [2] = x1T
    u16* BpT    = (u16*)nextp(2L * B_ * T_ * 3 * C_);
    u16* gxAll  = (u16*)nextp(2L * 3 * B_ * IT);   // (z, I, T)
    u16* thAll  = (u16*)nextp(2L * 3 * B_ * TI);   // (z, T, I)
    u16* phAll  = (u16*)nextp(2L * 3 * B_ * TI);
    u16* YT     = (u16*)nextp(2L * B_ * T_ * 3 * I_);
    u16* w_trb  = (u16*)nextp(2L * C_ * C_);
    u16* w_tcb  = (u16*)nextp(2L * 2 * C_ * 3 * C_);
    u16* w_gb   = (u16*)nextp(2L * 3 * I_ * C_);
    u16* w_thb  = (u16*)nextp(2L * 3 * I_ * C_);
    u16* w_phb  = (u16*)nextp(2L * 3 * I_ * C_);
    u16* w_Wb   = (u16*)nextp(2L * C_ * 3 * I_);
    float* meanb = (float*)nextp(4L * C_);
    float* rstdb = (float*)nextp(4L * C_);

    u16* x1T = txAll + 2L * B_ * TC;   // branch 2 input = x1 itself

    auto cvt = [&](const float* s, u16* d, long n) {
        to_f16<<<(int)((n / 4 + 255) / 256), 256, 0, stream>>>(s, d, n / 4);
    };
    cvt(w_tr, w_trb, (long)C_ * C_);
    cvt(w_tc, w_tcb, 2L * C_ * 3 * C_);
    cvt(w_g,  w_gb,  3L * I_ * C_);
    cvt(w_th, w_thb, 3L * I_ * C_);
    cvt(w_ph, w_phb, 3L * I_ * C_);
    cvt(w_W,  w_Wb,  (long)C_ * 3 * I_);

    peT_kernel<<<(T_ * C_) / 256, 256, 0, stream>>>(peT);
    xpose_add<<<dim3(T_ / 64, C_ / 64, B_), 256, 0, stream>>>(x, peT, xpeT);

    // x1 = relu(w_tr @ xpe + b_tr) -> x1n (C,T) + x1T (T,C)
    mfma_gemm<6, true, true><<<dim3(16, 4, 8), 256, 0, stream>>>(
        w_trb, 0, 1, C_, xpeT, TC, C_, b_tr, 0,
        nullptr, x1n, CT, T_, x1T, TC, C_, 0, C_);

    // temporal convs as K=1536 GEMMs vs shifted-stacked x1T
    build_bpt<<<(int)(B_ * T_ * 3 * C_ / 8 / 256), 256, 0, stream>>>(x1T, BpT, 1);
    mfma_gemm<4, false, false><<<dim3(16, 4, 8), 256, 0, stream>>>(
        w_tcb, 0, 1, 3 * C_, BpT, 3 * TC, 3 * C_, nullptr, 0,
        nullptr, nullptr, 0, 0, txAll, TC, C_, 0, 3 * C_);
    build_bpt<<<(int)(B_ * T_ * 3 * C_ / 8 / 256), 256, 0, stream>>>(x1T, BpT, 2);
    mfma_gemm<4, false, false><<<dim3(16, 4, 8), 256, 0, stream>>>(
        w_tcb + (long)C_ * 3 * C_, 0, 1, 3 * C_, BpT, 3 * TC, 3 * C_, nullptr, 0,
        nullptr, nullptr, 0, 0, txAll + (long)B_ * TC, TC, C_, 0, 3 * C_);

    // batched projections over z = br*8+b (grid.z = 24, 3 blocks/CU)
    mfma_gemm<2, true, false><<<dim3(16, 2, 24), 256, 0, stream>>>(
        w_gb, (long)I_ * C_, 8, C_, txAll, TC, C_, b_g, I_,
        nullptr, gxAll, IT, T_, nullptr, 0, 0, 0, C_);
    mfma_gemm<4, true, false><<<dim3(16, 2, 24), 256, 0, stream>>>(
        w_thb, (long)I_ * C_, 8, C_, txAll, TC, C_, b_th, I_,
        nullptr, nullptr, 0, 0, thAll, TI, I_, 0, C_);
    mfma_gemm<4, true, false><<<dim3(16, 2, 24), 256, 0, stream>>>(
        w_phb, (long)I_ * C_, 8, C_, txAll, TC, C_, b_ph, I_,
        nullptr, nullptr, 0, 0, phAll, TI, I_, 0, C_);

    // fused attention: S, softmax, PV without materializing S
    flash_attn<<<dim3(16, 24), 512, 0, stream>>>(thAll, phAll, gxAll, YT);

    // wy = w_W @ Y + b_W -> d_out (f32)
    mfma_gemm<1, true, false><<<dim3(16, 4, 8), 256, 0, stream>>>(
        w_Wb, 0, 1, 3 * I_, YT, 3 * TI, 3 * I_, b_W, 0,
        out, nullptr, CT, T_, nullptr, 0, 0, 0, 3 * I_);

    stats_kernel<<<C_, 256, 0, stream>>>(out, meanb, rstdb);
    final_kernel<<<(int)(B_ * C_ * T_ / 4 / 256), 256, 0, stream>>>(
        out, x1n, meanb, rstdb, gamma, beta);
}